// Round 4
// baseline (77.879 us; speedup 1.0000x reference)
//
#include <hip/hip_runtime.h>

// LCALayer: per-row (N=2e6, D=8) elementwise update.
// recur = sum(activities @ gamma) where gamma = -0.1 off-diag, 0 diag
//       = -0.1 * (8*S - S) = -0.7 * S,  S = row-sum of activities.
// active = all(|activities| < 1) ? 1 : 0
// pre = pa + (inp - 0.1*pa + recur) * active * 0.01 + nr * active * sqrt(0.001)
// act = relu(pre)
//
// R3 post-mortem: NT stores inflated WRITE_SIZE 135->152 MB (bypassing L2
// defeats write-combining of 32B half-lines) and did NOT reduce FETCH_SIZE.
// R4: revert to normal cached stores; keep one-thread-per-row launch (the
// part of R1 that actually helped: 78.4 -> 72.7 us).

#define THRESHOLD 1.0f
#define LEAK 0.1f
#define TSTEP 0.01f
#define SQRT_STEP 0.031622776601683794f  // sqrt(0.001)

typedef float vfloat4 __attribute__((ext_vector_type(4)));

__global__ __launch_bounds__(256) void lca_kernel(
    const float* __restrict__ inp,
    const float* __restrict__ pa,
    const float* __restrict__ acts,
    const float* __restrict__ nr,
    float* __restrict__ out_pre,
    float* __restrict__ out_act,
    float* __restrict__ out_active,
    int n)
{
    const int row = blockIdx.x * blockDim.x + threadIdx.x;
    if (row >= n) return;
    const size_t base = (size_t)row * 8;

    // --- issue all loads up front (max memory-level parallelism) ---
    vfloat4 a0 = *reinterpret_cast<const vfloat4*>(acts + base);
    vfloat4 a1 = *reinterpret_cast<const vfloat4*>(acts + base + 4);
    vfloat4 i0 = *reinterpret_cast<const vfloat4*>(inp + base);
    vfloat4 i1 = *reinterpret_cast<const vfloat4*>(inp + base + 4);
    vfloat4 p0 = *reinterpret_cast<const vfloat4*>(pa + base);
    vfloat4 p1 = *reinterpret_cast<const vfloat4*>(pa + base + 4);
    vfloat4 n0 = *reinterpret_cast<const vfloat4*>(nr + base);
    vfloat4 n1 = *reinterpret_cast<const vfloat4*>(nr + base + 4);

    float a[8] = {a0.x, a0.y, a0.z, a0.w, a1.x, a1.y, a1.z, a1.w};

    bool all_below = true;
    float S = 0.0f;
#pragma unroll
    for (int j = 0; j < 8; ++j) {
        all_below = all_below && (fabsf(a[j]) < THRESHOLD);
        S += a[j];
    }
    const float active = all_below ? 1.0f : 0.0f;
    const float recur = -0.7f * S;

    float iv[8] = {i0.x, i0.y, i0.z, i0.w, i1.x, i1.y, i1.z, i1.w};
    float pv[8] = {p0.x, p0.y, p0.z, p0.w, p1.x, p1.y, p1.z, p1.w};
    float nv[8] = {n0.x, n0.y, n0.z, n0.w, n1.x, n1.y, n1.z, n1.w};

    const float ts_a = active * TSTEP;       // (x * active) * 0.01
    const float ns_a = active * SQRT_STEP;   // noise scale

    float pr[8], ac[8];
#pragma unroll
    for (int j = 0; j < 8; ++j) {
        float x = iv[j] - LEAK * pv[j] + recur;
        float p = pv[j] + x * ts_a;
        p = p + nv[j] * ns_a;
        pr[j] = p;
        ac[j] = fmaxf(p, 0.0f);
    }

    vfloat4 pr0 = {pr[0], pr[1], pr[2], pr[3]};
    vfloat4 pr1 = {pr[4], pr[5], pr[6], pr[7]};
    vfloat4 ac0 = {ac[0], ac[1], ac[2], ac[3]};
    vfloat4 ac1 = {ac[4], ac[5], ac[6], ac[7]};

    *reinterpret_cast<vfloat4*>(out_pre + base)     = pr0;
    *reinterpret_cast<vfloat4*>(out_pre + base + 4) = pr1;
    *reinterpret_cast<vfloat4*>(out_act + base)     = ac0;
    *reinterpret_cast<vfloat4*>(out_act + base + 4) = ac1;
    out_active[row] = active;
}

extern "C" void kernel_launch(void* const* d_in, const int* in_sizes, int n_in,
                              void* d_out, int out_size, void* d_ws, size_t ws_size,
                              hipStream_t stream) {
    const float* inp  = (const float*)d_in[0];
    const float* pa   = (const float*)d_in[1];
    const float* acts = (const float*)d_in[2];
    const float* nr   = (const float*)d_in[3];

    const int n = in_sizes[0] / 8;  // 2,000,000 rows

    float* out = (float*)d_out;
    float* out_pre    = out;                    // [n, 8]
    float* out_act    = out + (size_t)n * 8;    // [n, 8]
    float* out_active = out + (size_t)n * 16;   // [n, 1]

    const int block = 256;
    const int grid = (n + block - 1) / block;   // one thread per row
    lca_kernel<<<grid, block, 0, stream>>>(inp, pa, acts, nr,
                                           out_pre, out_act, out_active, n);
}

// Round 5
// 67.047 us; speedup vs baseline: 1.1616x; 1.1616x over previous
//
#include <hip/hip_runtime.h>

// LCALayer: per-row (N=2e6, D=8) elementwise update.
// recur = sum(activities @ gamma) = -0.7 * rowsum(activities)
// active = all(|activities| < 1) ? 1 : 0
// pre = pa + (inp - 0.1*pa + recur) * active * 0.01 + nr * active * sqrt(0.001)
// act = relu(pre)
//
// R4 post-mortem: NT stores were the real R3 win (72.7 vs 77.9 cached) —
// L2 write-allocate pollution costs more than the +17MB HBM write traffic.
// R5: NT stores reinstated + 2 rows/thread (block = 512 consecutive rows in
// two wave-strips; every ld/st instruction stays 1KB-contiguous per wave).
// 16 loads in flight per thread for latency hiding.

#define THRESHOLD 1.0f
#define LEAK 0.1f
#define TSTEP 0.01f
#define SQRT_STEP 0.031622776601683794f  // sqrt(0.001)

typedef float vfloat4 __attribute__((ext_vector_type(4)));

__device__ __forceinline__ void lca_row(
    const vfloat4& va0, const vfloat4& va1,
    const vfloat4& vi0, const vfloat4& vi1,
    const vfloat4& vp0, const vfloat4& vp1,
    const vfloat4& vn0, const vfloat4& vn1,
    vfloat4& pr0, vfloat4& pr1, vfloat4& ac0, vfloat4& ac1,
    float& active_out)
{
    float a[8] = {va0.x, va0.y, va0.z, va0.w, va1.x, va1.y, va1.z, va1.w};
    bool all_below = true;
    float S = 0.0f;
#pragma unroll
    for (int j = 0; j < 8; ++j) {
        all_below = all_below && (fabsf(a[j]) < THRESHOLD);
        S += a[j];
    }
    const float active = all_below ? 1.0f : 0.0f;
    const float recur = -0.7f * S;

    float iv[8] = {vi0.x, vi0.y, vi0.z, vi0.w, vi1.x, vi1.y, vi1.z, vi1.w};
    float pv[8] = {vp0.x, vp0.y, vp0.z, vp0.w, vp1.x, vp1.y, vp1.z, vp1.w};
    float nv[8] = {vn0.x, vn0.y, vn0.z, vn0.w, vn1.x, vn1.y, vn1.z, vn1.w};

    const float ts_a = active * TSTEP;
    const float ns_a = active * SQRT_STEP;

    float pr[8], ac[8];
#pragma unroll
    for (int j = 0; j < 8; ++j) {
        float x = iv[j] - LEAK * pv[j] + recur;
        float p = pv[j] + x * ts_a + nv[j] * ns_a;
        pr[j] = p;
        ac[j] = fmaxf(p, 0.0f);
    }
    pr0 = (vfloat4){pr[0], pr[1], pr[2], pr[3]};
    pr1 = (vfloat4){pr[4], pr[5], pr[6], pr[7]};
    ac0 = (vfloat4){ac[0], ac[1], ac[2], ac[3]};
    ac1 = (vfloat4){ac[4], ac[5], ac[6], ac[7]};
    active_out = active;
}

__global__ __launch_bounds__(256) void lca_kernel(
    const float* __restrict__ inp,
    const float* __restrict__ pa,
    const float* __restrict__ acts,
    const float* __restrict__ nr,
    float* __restrict__ out_pre,
    float* __restrict__ out_act,
    float* __restrict__ out_active,
    int n)
{
    // block handles 512 consecutive rows: tid covers row rA, rA+256
    const int rA = blockIdx.x * 512 + threadIdx.x;
    const int rB = rA + 256;
    const size_t bA = (size_t)rA * 8;
    const size_t bB = (size_t)rB * 8;
    const bool okA = rA < n;
    const bool okB = rB < n;

    // issue ALL loads up front (up to 16 outstanding per thread)
    vfloat4 Aa0{}, Aa1{}, Ai0{}, Ai1{}, Ap0{}, Ap1{}, An0{}, An1{};
    vfloat4 Ba0{}, Ba1{}, Bi0{}, Bi1{}, Bp0{}, Bp1{}, Bn0{}, Bn1{};
    if (okA) {
        Aa0 = *reinterpret_cast<const vfloat4*>(acts + bA);
        Aa1 = *reinterpret_cast<const vfloat4*>(acts + bA + 4);
        Ai0 = *reinterpret_cast<const vfloat4*>(inp + bA);
        Ai1 = *reinterpret_cast<const vfloat4*>(inp + bA + 4);
        Ap0 = *reinterpret_cast<const vfloat4*>(pa + bA);
        Ap1 = *reinterpret_cast<const vfloat4*>(pa + bA + 4);
        An0 = *reinterpret_cast<const vfloat4*>(nr + bA);
        An1 = *reinterpret_cast<const vfloat4*>(nr + bA + 4);
    }
    if (okB) {
        Ba0 = *reinterpret_cast<const vfloat4*>(acts + bB);
        Ba1 = *reinterpret_cast<const vfloat4*>(acts + bB + 4);
        Bi0 = *reinterpret_cast<const vfloat4*>(inp + bB);
        Bi1 = *reinterpret_cast<const vfloat4*>(inp + bB + 4);
        Bp0 = *reinterpret_cast<const vfloat4*>(pa + bB);
        Bp1 = *reinterpret_cast<const vfloat4*>(pa + bB + 4);
        Bn0 = *reinterpret_cast<const vfloat4*>(nr + bB);
        Bn1 = *reinterpret_cast<const vfloat4*>(nr + bB + 4);
    }

    if (okA) {
        vfloat4 pr0, pr1, ac0, ac1; float act;
        lca_row(Aa0, Aa1, Ai0, Ai1, Ap0, Ap1, An0, An1, pr0, pr1, ac0, ac1, act);
        __builtin_nontemporal_store(pr0, reinterpret_cast<vfloat4*>(out_pre + bA));
        __builtin_nontemporal_store(pr1, reinterpret_cast<vfloat4*>(out_pre + bA + 4));
        __builtin_nontemporal_store(ac0, reinterpret_cast<vfloat4*>(out_act + bA));
        __builtin_nontemporal_store(ac1, reinterpret_cast<vfloat4*>(out_act + bA + 4));
        __builtin_nontemporal_store(act, out_active + rA);
    }
    if (okB) {
        vfloat4 pr0, pr1, ac0, ac1; float act;
        lca_row(Ba0, Ba1, Bi0, Bi1, Bp0, Bp1, Bn0, Bn1, pr0, pr1, ac0, ac1, act);
        __builtin_nontemporal_store(pr0, reinterpret_cast<vfloat4*>(out_pre + bB));
        __builtin_nontemporal_store(pr1, reinterpret_cast<vfloat4*>(out_pre + bB + 4));
        __builtin_nontemporal_store(ac0, reinterpret_cast<vfloat4*>(out_act + bB));
        __builtin_nontemporal_store(ac1, reinterpret_cast<vfloat4*>(out_act + bB + 4));
        __builtin_nontemporal_store(act, out_active + rB);
    }
}

extern "C" void kernel_launch(void* const* d_in, const int* in_sizes, int n_in,
                              void* d_out, int out_size, void* d_ws, size_t ws_size,
                              hipStream_t stream) {
    const float* inp  = (const float*)d_in[0];
    const float* pa   = (const float*)d_in[1];
    const float* acts = (const float*)d_in[2];
    const float* nr   = (const float*)d_in[3];

    const int n = in_sizes[0] / 8;  // 2,000,000 rows

    float* out = (float*)d_out;
    float* out_pre    = out;                    // [n, 8]
    float* out_act    = out + (size_t)n * 8;    // [n, 8]
    float* out_active = out + (size_t)n * 16;   // [n, 1]

    const int block = 256;
    const int grid = (n + 511) / 512;           // 2 rows per thread
    lca_kernel<<<grid, block, 0, stream>>>(inp, pa, acts, nr,
                                           out_pre, out_act, out_active, n);
}